// Round 14
// baseline (5375.891 us; speedup 1.0000x reference)
//
#include <hip/hip_runtime.h>
#include <math.h>

#define BB 64
#define TT 512
#define FF 32
#define HH 512
#define OO 680

typedef _Float16 half8 __attribute__((ext_vector_type(8)));
typedef float f32x4 __attribute__((ext_vector_type(4)));

// ---- ws layout: act slabs in MFMA-B-fragment tile order ----
// tile(ks,bfrag) = 1KB; lane l owns 16B at l*16: k = ks*32+(l>>4)*8+j, batch = bfrag*16+(l&15).
#define H1SLAB 65536u
#define C1SLAB 65536u
#define H2SLAB 90112u                  // 22 k-tiles (680 cols zero-padded to 704)
#define H1S_OFF 0u                     // 2 buffers (ping-pong, L1-internal)
#define C1S_OFF 131072u                // 4-deep ring (L1 -> L2, decoupled)
#define H2S_OFF 393216u                // 2 buffers (ping-pong, L2-internal)
#define BAR_OFF 573440u
#define MEMSET_BYTES 576000u

#define L1B  16                        // blocks [0,16): L1, 32 cols each
#define NBLK 59                        // blocks [16,59): L2, 16 cols each
#define LDS_BYTES 155648u              // L2 weight slab 152KB (L1 uses 136KB)

// Monotonic arrival counters, one 128B line each. Per-WAVE arrivals.
// L1: 2 groups x 8 blocks x 4 waves = 32 arrivals/epoch/group.
// L2: groups 0-2 have 6 blocks (24 arrivals), 3-7 have 5 (20 arrivals).
#define L1CNT(g) ((g)*32)              // g = 0..1
#define L2CNT(g) (64 + (g)*32)         // g = 0..7

__device__ __forceinline__ float sigf(float x) { return 1.f / (1.f + expf(-x)); }

__device__ __forceinline__ unsigned al32(const unsigned* p) {
    return __hip_atomic_load(p, __ATOMIC_RELAXED, __HIP_MEMORY_SCOPE_AGENT);
}
__device__ __forceinline__ unsigned long long aload8(const void* p) {
    return __hip_atomic_load((const unsigned long long*)p, __ATOMIC_RELAXED, __HIP_MEMORY_SCOPE_AGENT);
}
__device__ __forceinline__ void astore8(void* p, unsigned long long v) {
    __hip_atomic_store((unsigned long long*)p, v, __ATOMIC_RELAXED, __HIP_MEMORY_SCOPE_AGENT);
}
__device__ __forceinline__ half8 ld_act(const char* p) {
    union { unsigned long long u[2]; half8 h; } t;
    t.u[0] = aload8(p); t.u[1] = aload8(p + 8);
    return t.h;
}
__device__ __forceinline__ unsigned pack2h(float a, float b) {
    union { _Float16 h[2]; unsigned u; } t;
    t.h[0] = (_Float16)a; t.h[1] = (_Float16)b; return t.u;
}
__device__ __forceinline__ unsigned long long pack4h(float a, float b, float c, float d) {
    union { _Float16 h[4]; unsigned long long u; } t;
    t.h[0] = (_Float16)a; t.h[1] = (_Float16)b; t.h[2] = (_Float16)c; t.h[3] = (_Float16)d;
    return t.u;
}

// Wave-uniform spin: all lanes load the same address (coalesces to 1 request).
__device__ __forceinline__ void wait2_ge(const unsigned* p0, const unsigned* p1, unsigned tgt) {
    for (;;) {
        const unsigned a = al32(p0), b = al32(p1);
        if (a >= tgt && b >= tgt) return;
        __builtin_amdgcn_s_sleep(1);
    }
}
// Epoch e of the L2 domain complete?  (counters monotonic, per-wave arrivals)
__device__ __forceinline__ bool l2done(const unsigned* bar, unsigned e) {
    unsigned ok = 1u;
    ok &= (al32(bar + L2CNT(0)) >= e * 24u);
    ok &= (al32(bar + L2CNT(1)) >= e * 24u);
    ok &= (al32(bar + L2CNT(2)) >= e * 24u);
    ok &= (al32(bar + L2CNT(3)) >= e * 20u);
    ok &= (al32(bar + L2CNT(4)) >= e * 20u);
    ok &= (al32(bar + L2CNT(5)) >= e * 20u);
    ok &= (al32(bar + L2CNT(6)) >= e * 20u);
    ok &= (al32(bar + L2CNT(7)) >= e * 20u);
    return ok != 0u;
}

// Persistent MFMA kernel, 59 blocks x 256 threads, weights LDS-resident.
// Split sync domains; per-WAVE arrival/detect (no per-step __syncthreads);
// x/c1 partial GEMMs hoisted before the recurrence waits.
__global__ __launch_bounds__(256, 1)
void rnn_mfma(const float* __restrict__ data,
    const float* __restrict__ Wih1, const float* __restrict__ Whh1,
    const float* __restrict__ bih1, const float* __restrict__ bhh1,
    const float* __restrict__ Wih2, const float* __restrict__ Whh2,
    const float* __restrict__ bih2, const float* __restrict__ bhh2,
    char* __restrict__ wsb, float* __restrict__ out)
{
    extern __shared__ char lds[];
    const int tid = threadIdx.x, wv = tid >> 6, l = tid & 63;
    const int hi = l >> 4, lo = l & 15;
    const int blk = blockIdx.x;
    unsigned* bar = (unsigned*)(wsb + BAR_OFF);
    const int bfrag = wv;              // wave = batch-fragment
    const int b = bfrag * 16 + lo;     // this lane's batch

    if (blk < L1B) {
        // ================= LAYER-1 BLOCK: 32 cols =================
        const int c0 = blk * 32;
        for (int u = tid; u < 136 * 256; u += 256) {   // weights -> LDS (fp16, A-frag tiles)
            const int tile = u >> 8, w = u & 255;
            const int ll = w >> 2, jj = w & 3;
            const int ks = tile >> 3, rest = tile & 7; // rest = gate*2 + chi
            const int gate = rest >> 1, chi = rest & 1;
            const int col = c0 + chi * 16 + (ll & 15);
            const int row = gate * HH + col;
            const int kk = ks * 32 + (ll >> 4) * 8 + jj * 2;
            const float v0 = (kk < FF)     ? Wih1[(size_t)row * FF + kk]     : Whh1[(size_t)row * HH + kk - FF];
            const float v1 = (kk + 1 < FF) ? Wih1[(size_t)row * FF + kk + 1] : Whh1[(size_t)row * HH + kk + 1 - FF];
            ((unsigned*)lds)[tile * 256 + w] = pack2h(v0, v1);
        }
        __syncthreads();

        float bs[2][4][4];
        #pragma unroll
        for (int chi = 0; chi < 2; ++chi)
            #pragma unroll
            for (int r = 0; r < 4; ++r) {
                const int col = c0 + chi * 16 + hi * 4 + r;
                #pragma unroll
                for (int g = 0; g < 4; ++g)
                    bs[chi][r][g] = bih1[g * HH + col] + bhh1[g * HH + col];
            }
        float cr[8] = {0.f,0.f,0.f,0.f,0.f,0.f,0.f,0.f};

        for (int s = 0; s < TT; ++s) {
            const int pr = s & 1;
            // ---- x part: loads + MFMAs BEFORE the recurrence wait ----
            const float* xp = data + (size_t)b * (TT * FF) + (size_t)s * FF + hi * 8;
            const float4 xa = *(const float4*)xp;
            const float4 xb4 = *(const float4*)(xp + 4);
            half8 bx;
            bx[0] = (_Float16)xa.x; bx[1] = (_Float16)xa.y; bx[2] = (_Float16)xa.z; bx[3] = (_Float16)xa.w;
            bx[4] = (_Float16)xb4.x; bx[5] = (_Float16)xb4.y; bx[6] = (_Float16)xb4.z; bx[7] = (_Float16)xb4.w;
            f32x4 acc[8];
            #pragma unroll
            for (int a = 0; a < 8; ++a) acc[a] = (f32x4){0.f,0.f,0.f,0.f};
            #pragma unroll
            for (int a = 0; a < 8; ++a)
                acc[a] = __builtin_amdgcn_mfma_f32_16x16x32_f16(*(const half8*)(lds + (size_t)a * 1024 + (size_t)l * 16), bx, acc[a], 0, 0, 0);

            // ---- own-domain wait: h1(s-1) published by all 16 blocks ----
            if (s > 0) wait2_ge(bar + L1CNT(0), bar + L1CNT(1), (unsigned)s * 32u);

            const char* h1p = wsb + H1S_OFF + (size_t)pr * H1SLAB + (size_t)l * 16;
            #pragma unroll
            for (int ks = 1; ks <= 16; ++ks) {
                const half8 bf = ld_act(h1p + (size_t)((ks - 1) * 4 + bfrag) * 1024);
                #pragma unroll
                for (int a = 0; a < 8; ++a)
                    acc[a] = __builtin_amdgcn_mfma_f32_16x16x32_f16(*(const half8*)(lds + (size_t)(ks * 8 + a) * 1024 + (size_t)l * 16), bf, acc[a], 0, 0, 0);
            }
            // ---- throttle: c1 ring slot must be consumed (L1 has 3-step slack;
            //      lazy poll with long sleep — precision irrelevant off-path) ----
            if (s > 3) {
                const unsigned e = (unsigned)(s - 3);
                while (!l2done(bar, e)) __builtin_amdgcn_s_sleep(8);
            }
            // ---- lane-local epilogue ----
            char* h1w = wsb + H1S_OFF + (size_t)(pr ^ 1) * H1SLAB;
            char* c1w = wsb + C1S_OFF + (size_t)(s & 3) * C1SLAB;
            #pragma unroll
            for (int chi = 0; chi < 2; ++chi) {
                const int cc = c0 + chi * 16 + hi * 4;
                float cn[4], hn[4];
                #pragma unroll
                for (int r = 0; r < 4; ++r) {
                    const float ig = sigf(acc[0 + chi][r] + bs[chi][r][0]);
                    const float fg = sigf(acc[2 + chi][r] + bs[chi][r][1]);
                    const float gg = tanhf(acc[4 + chi][r] + bs[chi][r][2]);
                    const float og = sigf(acc[6 + chi][r] + bs[chi][r][3]);
                    const float c = fg * cr[chi * 4 + r] + ig * gg;
                    cr[chi * 4 + r] = c;
                    cn[r] = c; hn[r] = og * tanhf(c);
                }
                const size_t aoff = (size_t)((cc >> 5) * 4 + bfrag) * 1024
                                  + (size_t)((((cc >> 3) & 3) * 16 + lo)) * 16
                                  + (size_t)(cc & 7) * 2;
                astore8(h1w + aoff, pack4h(hn[0], hn[1], hn[2], hn[3]));
                astore8(c1w + aoff, pack4h(cn[0], cn[1], cn[2], cn[3]));
            }
            // ---- per-wave arrival: own stores drained, one RMW ----
            __builtin_amdgcn_s_waitcnt(0);
            if (l == 0)
                __hip_atomic_fetch_add(bar + L1CNT(blk & 1), 1u, __ATOMIC_RELAXED, __HIP_MEMORY_SCOPE_AGENT);
        }
    } else {
        // ================= LAYER-2 BLOCK: 16 cols =================
        const int idx = blk - L1B, c0 = idx * 16;
        const int grp = idx & 7;
        for (int u = tid; u < 152 * 256; u += 256) {   // weights -> LDS
            const int tile = u >> 8, w = u & 255;
            const int ll = w >> 2, jj = w & 3;
            const int ks = tile >> 2, gate = tile & 3;
            const int col = c0 + (ll & 15);
            const int kk = ks * 32 + (ll >> 4) * 8 + jj * 2;
            float v0 = 0.f, v1 = 0.f;
            if (col < OO) {
                if (kk < HH) v0 = Wih2[((size_t)gate * OO + col) * HH + kk];
                else if (kk < 1192) v0 = Whh2[((size_t)gate * OO + col) * OO + kk - HH];
                if (kk + 1 < HH) v1 = Wih2[((size_t)gate * OO + col) * HH + kk + 1];
                else if (kk + 1 < 1192) v1 = Whh2[((size_t)gate * OO + col) * OO + kk + 1 - HH];
            }
            ((unsigned*)lds)[tile * 256 + w] = pack2h(v0, v1);
        }
        __syncthreads();

        const int cc = c0 + hi * 4;
        float bs[4][4];
        #pragma unroll
        for (int r = 0; r < 4; ++r) {
            const int col = cc + r;
            const bool ok = col < OO;
            #pragma unroll
            for (int g = 0; g < 4; ++g)
                bs[r][g] = ok ? (bih2[g * OO + col] + bhh2[g * OO + col]) : 0.f;
        }
        float cr[4] = {0.f,0.f,0.f,0.f};

        for (int t = 1; t <= TT; ++t) {
            // (A) c1(t-1) ready? (L1 runs ahead -> normally one check)
            wait2_ge(bar + L1CNT(0), bar + L1CNT(1), (unsigned)t * 32u);
            // (B) c1 loads + c1-part MFMAs — all BEFORE the h2 wait
            const char* c1p = wsb + C1S_OFF + (size_t)((t - 1) & 3) * C1SLAB + (size_t)l * 16;
            half8 bcs[16];
            #pragma unroll
            for (int ks = 0; ks < 16; ++ks) bcs[ks] = ld_act(c1p + (size_t)(ks * 4 + bfrag) * 1024);
            f32x4 acc[4];
            #pragma unroll
            for (int g = 0; g < 4; ++g) acc[g] = (f32x4){0.f,0.f,0.f,0.f};
            #pragma unroll
            for (int ks = 0; ks < 16; ++ks) {
                #pragma unroll
                for (int g = 0; g < 4; ++g)
                    acc[g] = __builtin_amdgcn_mfma_f32_16x16x32_f16(*(const half8*)(lds + (size_t)(ks * 4 + g) * 1024 + (size_t)l * 16), bcs[ks], acc[g], 0, 0, 0);
            }
            // (C) h2(t-1) handoff — the pacing wait
            {
                const unsigned e = (unsigned)(t - 1);
                while (!l2done(bar, e)) __builtin_amdgcn_s_sleep(1);
            }
            // (D) h2 loads + h2-part MFMAs
            const char* h2p = wsb + H2S_OFF + (size_t)((t & 1) ^ 1) * H2SLAB + (size_t)l * 16;
            half8 bhs[22];
            #pragma unroll
            for (int ks = 0; ks < 22; ++ks) bhs[ks] = ld_act(h2p + (size_t)(ks * 4 + bfrag) * 1024);
            #pragma unroll
            for (int ks = 0; ks < 22; ++ks) {
                #pragma unroll
                for (int g = 0; g < 4; ++g)
                    acc[g] = __builtin_amdgcn_mfma_f32_16x16x32_f16(*(const half8*)(lds + (size_t)((16 + ks) * 4 + g) * 1024 + (size_t)l * 16), bhs[ks], acc[g], 0, 0, 0);
            }
            // (E) lane-local epilogue: out + h2
            if (cc < OO) {
                const int u_ = t - 1;
                float cn[4], hn[4];
                #pragma unroll
                for (int r = 0; r < 4; ++r) {
                    const float ig = sigf(acc[0][r] + bs[r][0]);
                    const float fg = sigf(acc[1][r] + bs[r][1]);
                    const float gg = tanhf(acc[2][r] + bs[r][2]);
                    const float og = sigf(acc[3][r] + bs[r][3]);
                    const float c = fg * cr[r] + ig * gg;
                    cr[r] = c;
                    cn[r] = c; hn[r] = og * tanhf(c);
                }
                const f32x4 q = {cn[0], cn[1], cn[2], cn[3]};
                __builtin_nontemporal_store(q, (f32x4*)(out + (size_t)b * (TT * OO) + (size_t)u_ * OO + cc));
                char* h2w = wsb + H2S_OFF + (size_t)(t & 1) * H2SLAB;
                const size_t aoff = (size_t)((cc >> 5) * 4 + bfrag) * 1024
                                  + (size_t)((((cc >> 3) & 3) * 16 + lo)) * 16
                                  + (size_t)(cc & 7) * 2;
                astore8(h2w + aoff, pack4h(hn[0], hn[1], hn[2], hn[3]));
            }
            // (F) per-wave arrival (skip final epoch; nobody waits on it)
            __builtin_amdgcn_s_waitcnt(0);
            if (t < TT && l == 0)
                __hip_atomic_fetch_add(bar + L2CNT(grp), 1u, __ATOMIC_RELAXED, __HIP_MEMORY_SCOPE_AGENT);
        }
    }
}

extern "C" void kernel_launch(void* const* d_in, const int* in_sizes, int n_in,
                              void* d_out, int out_size, void* d_ws, size_t ws_size,
                              hipStream_t stream)
{
    const float* data = (const float*)d_in[0];
    const float* Wih1 = (const float*)d_in[1];
    const float* Whh1 = (const float*)d_in[2];
    const float* bih1 = (const float*)d_in[3];
    const float* bhh1 = (const float*)d_in[4];
    const float* Wih2 = (const float*)d_in[5];
    const float* Whh2 = (const float*)d_in[6];
    const float* bih2 = (const float*)d_in[7];
    const float* bhh2 = (const float*)d_in[8];
    float* out = (float*)d_out;
    char* wsb  = (char*)d_ws;

    hipFuncSetAttribute((const void*)rnn_mfma, hipFuncAttributeMaxDynamicSharedMemorySize, (int)LDS_BYTES);
    hipMemsetAsync(wsb, 0, MEMSET_BYTES, stream);   // slabs + counters: replay-safe
    rnn_mfma<<<NBLK, 256, LDS_BYTES, stream>>>(data,
                                               Wih1, Whh1, bih1, bhh1,
                                               Wih2, Whh2, bih2, bhh2,
                                               wsb, out);
}

// Round 15
// 4450.327 us; speedup vs baseline: 1.2080x; 1.2080x over previous
//
#include <hip/hip_runtime.h>
#include <math.h>

#define BB 64
#define TT 512
#define FF 32
#define HH 512
#define OO 680

typedef _Float16 half8 __attribute__((ext_vector_type(8)));
typedef float f32x4 __attribute__((ext_vector_type(4)));

// ---- ws layout: act slabs in MFMA-B-fragment tile order ----
// tile(ks,bfrag) = 1KB; lane l owns 16B at l*16: k = ks*32+(l>>4)*8+j, batch = bfrag*16+(l&15).
#define H1SLAB 65536u
#define C1SLAB 65536u
#define H2SLAB 90112u                  // 22 k-tiles (680 cols zero-padded to 704)
#define H1S_OFF 0u                     // 2 buffers (ping-pong, L1-internal)
#define C1S_OFF 131072u                // 4-deep ring (L1 -> L2, decoupled)
#define H2S_OFF 393216u                // 2 buffers (ping-pong, L2-internal)
#define BAR_OFF 573440u
#define MEMSET_BYTES 576000u

#define L1B  16                        // blocks [0,16): L1, 32 cols each
#define NBLK 59                        // blocks [16,59): L2, 16 cols each
#define LDS_BYTES 155648u              // L2 weight slab 152KB (L1 uses 136KB)

// bar word offsets: counters on distinct 128B lines, flags packed per domain.
// Arrivals are per-BLOCK (tid0), R13-proven. Pollers read only flag lines.
#define L1CNT(g) ((g)*32)              // g=0..1, 8 blocks each
#define L1FLG    64                    // 2 dwords, one line (read-mostly)
#define L2CNT(g) (96 + (g)*32)         // g=0..7
#define L2FLG    352                   // 8 dwords, one line (read-mostly)

__device__ __forceinline__ float sigf(float x) { return 1.f / (1.f + expf(-x)); }

__device__ __forceinline__ unsigned long long aload8(const void* p) {
    return __hip_atomic_load((const unsigned long long*)p, __ATOMIC_RELAXED, __HIP_MEMORY_SCOPE_AGENT);
}
__device__ __forceinline__ void astore8(void* p, unsigned long long v) {
    __hip_atomic_store((unsigned long long*)p, v, __ATOMIC_RELAXED, __HIP_MEMORY_SCOPE_AGENT);
}
__device__ __forceinline__ void astore32(unsigned* p, unsigned v) {
    __hip_atomic_store(p, v, __ATOMIC_RELAXED, __HIP_MEMORY_SCOPE_AGENT);
}
__device__ __forceinline__ half8 ld_act(const char* p) {
    union { unsigned long long u[2]; half8 h; } t;
    t.u[0] = aload8(p); t.u[1] = aload8(p + 8);
    return t.h;
}
__device__ __forceinline__ unsigned pack2h(float a, float b) {
    union { _Float16 h[2]; unsigned u; } t;
    t.h[0] = (_Float16)a; t.h[1] = (_Float16)b; return t.u;
}
__device__ __forceinline__ unsigned long long pack4h(float a, float b, float c, float d) {
    union { _Float16 h[4]; unsigned long long u; } t;
    t.h[0] = (_Float16)a; t.h[1] = (_Float16)b; t.h[2] = (_Float16)c; t.h[3] = (_Float16)d;
    return t.u;
}
__device__ __forceinline__ unsigned minL1(const unsigned* bar) {
    const unsigned long long v = aload8(bar + L1FLG);
    const unsigned a = (unsigned)v, b = (unsigned)(v >> 32);
    return a < b ? a : b;
}
__device__ __forceinline__ unsigned minL2(const unsigned* bar) {
    const unsigned long long v0 = aload8(bar + L2FLG);
    const unsigned long long v1 = aload8(bar + L2FLG + 2);
    const unsigned long long v2 = aload8(bar + L2FLG + 4);
    const unsigned long long v3 = aload8(bar + L2FLG + 6);
    unsigned m = (unsigned)v0;
    unsigned x;
    x = (unsigned)(v0 >> 32); m = x < m ? x : m;
    x = (unsigned)v1;         m = x < m ? x : m;
    x = (unsigned)(v1 >> 32); m = x < m ? x : m;
    x = (unsigned)v2;         m = x < m ? x : m;
    x = (unsigned)(v2 >> 32); m = x < m ? x : m;
    x = (unsigned)v3;         m = x < m ? x : m;
    x = (unsigned)(v3 >> 32); m = x < m ? x : m;
    return m;
}

// Persistent MFMA kernel, 59 blocks x 256 threads, weights LDS-resident.
// R13 sync skeleton (per-block arrival, flag-line polling) + hoisted
// non-recurrent GEMM parts + cached c1 gate + deferred out-store.
__global__ __launch_bounds__(256, 1)
void rnn_mfma(const float* __restrict__ data,
    const float* __restrict__ Wih1, const float* __restrict__ Whh1,
    const float* __restrict__ bih1, const float* __restrict__ bhh1,
    const float* __restrict__ Wih2, const float* __restrict__ Whh2,
    const float* __restrict__ bih2, const float* __restrict__ bhh2,
    char* __restrict__ wsb, float* __restrict__ out)
{
    extern __shared__ char lds[];
    const int tid = threadIdx.x, wv = tid >> 6, l = tid & 63;
    const int hi = l >> 4, lo = l & 15;
    const int blk = blockIdx.x;
    unsigned* bar = (unsigned*)(wsb + BAR_OFF);
    const int bfrag = wv;              // wave = batch-fragment
    const int b = bfrag * 16 + lo;     // this lane's batch

    if (blk < L1B) {
        // ================= LAYER-1 BLOCK: 32 cols =================
        const int c0 = blk * 32;
        for (int u = tid; u < 136 * 256; u += 256) {   // weights -> LDS (fp16, A-frag tiles)
            const int tile = u >> 8, w = u & 255;
            const int ll = w >> 2, jj = w & 3;
            const int ks = tile >> 3, rest = tile & 7; // rest = gate*2 + chi
            const int gate = rest >> 1, chi = rest & 1;
            const int col = c0 + chi * 16 + (ll & 15);
            const int row = gate * HH + col;
            const int kk = ks * 32 + (ll >> 4) * 8 + jj * 2;
            const float v0 = (kk < FF)     ? Wih1[(size_t)row * FF + kk]     : Whh1[(size_t)row * HH + kk - FF];
            const float v1 = (kk + 1 < FF) ? Wih1[(size_t)row * FF + kk + 1] : Whh1[(size_t)row * HH + kk + 1 - FF];
            ((unsigned*)lds)[tile * 256 + w] = pack2h(v0, v1);
        }
        __syncthreads();

        float bs[2][4][4];
        #pragma unroll
        for (int chi = 0; chi < 2; ++chi)
            #pragma unroll
            for (int r = 0; r < 4; ++r) {
                const int col = c0 + chi * 16 + hi * 4 + r;
                #pragma unroll
                for (int g = 0; g < 4; ++g)
                    bs[chi][r][g] = bih1[g * HH + col] + bhh1[g * HH + col];
            }
        float cr[8] = {0.f,0.f,0.f,0.f,0.f,0.f,0.f,0.f};

        for (int s = 0; s < TT; ++s) {
            const int pr = s & 1;
            // ---- x part: loads + MFMAs fully BEFORE the recurrence wait ----
            const float* xp = data + (size_t)b * (TT * FF) + (size_t)s * FF + hi * 8;
            const float4 xa = *(const float4*)xp;
            const float4 xb4 = *(const float4*)(xp + 4);
            half8 bx;
            bx[0] = (_Float16)xa.x; bx[1] = (_Float16)xa.y; bx[2] = (_Float16)xa.z; bx[3] = (_Float16)xa.w;
            bx[4] = (_Float16)xb4.x; bx[5] = (_Float16)xb4.y; bx[6] = (_Float16)xb4.z; bx[7] = (_Float16)xb4.w;
            f32x4 acc[8];
            #pragma unroll
            for (int a = 0; a < 8; ++a) acc[a] = (f32x4){0.f,0.f,0.f,0.f};
            #pragma unroll
            for (int a = 0; a < 8; ++a)
                acc[a] = __builtin_amdgcn_mfma_f32_16x16x32_f16(*(const half8*)(lds + (size_t)a * 1024 + (size_t)l * 16), bx, acc[a], 0, 0, 0);

            // ---- own-domain wait: h1(s-1) published by all 16 blocks ----
            if (s > 0) {
                if (tid == 0) { while (minL1(bar) < (unsigned)s) {} }
                __syncthreads();
            }
            const char* h1p = wsb + H1S_OFF + (size_t)pr * H1SLAB + (size_t)l * 16;
            #pragma unroll
            for (int ks = 1; ks <= 16; ++ks) {
                const half8 bf = ld_act(h1p + (size_t)((ks - 1) * 4 + bfrag) * 1024);
                #pragma unroll
                for (int a = 0; a < 8; ++a)
                    acc[a] = __builtin_amdgcn_mfma_f32_16x16x32_f16(*(const half8*)(lds + (size_t)(ks * 8 + a) * 1024 + (size_t)l * 16), bf, acc[a], 0, 0, 0);
            }
            // ---- throttle: c1 ring slot must be consumed by L2 ----
            if (s > 3) {
                if (tid == 0) { while (minL2(bar) < (unsigned)(s - 3)) {} }
                __syncthreads();
            }
            // ---- lane-local epilogue ----
            char* h1w = wsb + H1S_OFF + (size_t)(pr ^ 1) * H1SLAB;
            char* c1w = wsb + C1S_OFF + (size_t)(s & 3) * C1SLAB;
            #pragma unroll
            for (int chi = 0; chi < 2; ++chi) {
                const int cc = c0 + chi * 16 + hi * 4;
                float cn[4], hn[4];
                #pragma unroll
                for (int r = 0; r < 4; ++r) {
                    const float ig = sigf(acc[0 + chi][r] + bs[chi][r][0]);
                    const float fg = sigf(acc[2 + chi][r] + bs[chi][r][1]);
                    const float gg = tanhf(acc[4 + chi][r] + bs[chi][r][2]);
                    const float og = sigf(acc[6 + chi][r] + bs[chi][r][3]);
                    const float c = fg * cr[chi * 4 + r] + ig * gg;
                    cr[chi * 4 + r] = c;
                    cn[r] = c; hn[r] = og * tanhf(c);
                }
                const size_t aoff = (size_t)((cc >> 5) * 4 + bfrag) * 1024
                                  + (size_t)((((cc >> 3) & 3) * 16 + lo)) * 16
                                  + (size_t)(cc & 7) * 2;
                astore8(h1w + aoff, pack4h(hn[0], hn[1], hn[2], hn[3]));
                astore8(c1w + aoff, pack4h(cn[0], cn[1], cn[2], cn[3]));
            }
            __syncthreads();   // drains all waves' stores
            if (tid == 0) {
                const int g = blk & 1;
                const unsigned e = (unsigned)(s + 1);
                const unsigned a2 = __hip_atomic_fetch_add(bar + L1CNT(g), 1u, __ATOMIC_RELAXED, __HIP_MEMORY_SCOPE_AGENT);
                if (a2 == e * 8u - 1u) astore32(bar + L1FLG + g, e);
            }
        }
    } else {
        // ================= LAYER-2 BLOCK: 16 cols =================
        const int idx = blk - L1B, c0 = idx * 16;
        const int grp = idx & 7;
        const unsigned gsz = (grp < 3) ? 6u : 5u;   // 43 = 3*6 + 5*5
        for (int u = tid; u < 152 * 256; u += 256) {   // weights -> LDS
            const int tile = u >> 8, w = u & 255;
            const int ll = w >> 2, jj = w & 3;
            const int ks = tile >> 2, gate = tile & 3;
            const int col = c0 + (ll & 15);
            const int kk = ks * 32 + (ll >> 4) * 8 + jj * 2;
            float v0 = 0.f, v1 = 0.f;
            if (col < OO) {
                if (kk < HH) v0 = Wih2[((size_t)gate * OO + col) * HH + kk];
                else if (kk < 1192) v0 = Whh2[((size_t)gate * OO + col) * OO + kk - HH];
                if (kk + 1 < HH) v1 = Wih2[((size_t)gate * OO + col) * HH + kk + 1];
                else if (kk + 1 < 1192) v1 = Whh2[((size_t)gate * OO + col) * OO + kk + 1 - HH];
            }
            ((unsigned*)lds)[tile * 256 + w] = pack2h(v0, v1);
        }
        __syncthreads();

        const int cc = c0 + hi * 4;
        float bs[4][4];
        #pragma unroll
        for (int r = 0; r < 4; ++r) {
            const int col = cc + r;
            const bool ok = col < OO;
            #pragma unroll
            for (int g = 0; g < 4; ++g)
                bs[r][g] = ok ? (bih2[g * OO + col] + bhh2[g * OO + col]) : 0.f;
        }
        float cr[4] = {0.f,0.f,0.f,0.f};
        unsigned l1seen = 0;               // cached L1 flag min (L1 runs >=3 ahead)

        for (int t = 1; t <= TT; ++t) {
            // (A) c1(t-1) ready? — per-wave CACHED gate: zero LLC traffic when
            //     the cached value already covers epoch t (common case).
            if (l1seen < (unsigned)t) {
                for (;;) {
                    const unsigned m = minL1(bar);   // wave-uniform load, 1 request
                    if (m >= (unsigned)t) { l1seen = m; break; }
                }
            }
            // (B) c1 loads + c1-part MFMAs — all BEFORE the h2 wait
            const char* c1p = wsb + C1S_OFF + (size_t)((t - 1) & 3) * C1SLAB + (size_t)l * 16;
            half8 bcs[16];
            #pragma unroll
            for (int ks = 0; ks < 16; ++ks) bcs[ks] = ld_act(c1p + (size_t)(ks * 4 + bfrag) * 1024);
            f32x4 acc[4];
            #pragma unroll
            for (int g = 0; g < 4; ++g) acc[g] = (f32x4){0.f,0.f,0.f,0.f};
            #pragma unroll
            for (int ks = 0; ks < 16; ++ks) {
                #pragma unroll
                for (int g = 0; g < 4; ++g)
                    acc[g] = __builtin_amdgcn_mfma_f32_16x16x32_f16(*(const half8*)(lds + (size_t)(ks * 4 + g) * 1024 + (size_t)l * 16), bcs[ks], acc[g], 0, 0, 0);
            }
            // (C) h2(t-1) handoff — the pacing wait (R13-proven form)
            if (t > 1) {
                if (tid == 0) { while (minL2(bar) < (unsigned)(t - 1)) {} }
                __syncthreads();
            }
            // (D) h2 loads + h2-part MFMAs
            const char* h2p = wsb + H2S_OFF + (size_t)((t & 1) ^ 1) * H2SLAB + (size_t)l * 16;
            half8 bhs[22];
            #pragma unroll
            for (int ks = 0; ks < 22; ++ks) bhs[ks] = ld_act(h2p + (size_t)(ks * 4 + bfrag) * 1024);
            #pragma unroll
            for (int ks = 0; ks < 22; ++ks) {
                #pragma unroll
                for (int g = 0; g < 4; ++g)
                    acc[g] = __builtin_amdgcn_mfma_f32_16x16x32_f16(*(const half8*)(lds + (size_t)((16 + ks) * 4 + g) * 1024 + (size_t)l * 16), bhs[ks], acc[g], 0, 0, 0);
            }
            // (E) lane-local epilogue: store h2 ONLY (out deferred past arrival)
            float cn[4];
            if (cc < OO) {
                float hn[4];
                #pragma unroll
                for (int r = 0; r < 4; ++r) {
                    const float ig = sigf(acc[0][r] + bs[r][0]);
                    const float fg = sigf(acc[1][r] + bs[r][1]);
                    const float gg = tanhf(acc[2][r] + bs[r][2]);
                    const float og = sigf(acc[3][r] + bs[r][3]);
                    const float c = fg * cr[r] + ig * gg;
                    cr[r] = c;
                    cn[r] = c; hn[r] = og * tanhf(c);
                }
                char* h2w = wsb + H2S_OFF + (size_t)(t & 1) * H2SLAB;
                const size_t aoff = (size_t)((cc >> 5) * 4 + bfrag) * 1024
                                  + (size_t)((((cc >> 3) & 3) * 16 + lo)) * 16
                                  + (size_t)(cc & 7) * 2;
                astore8(h2w + aoff, pack4h(hn[0], hn[1], hn[2], hn[3]));
            }
            // (F) arrival: h2 stores drained by the barrier; one RMW per block
            __syncthreads();
            if (t < TT && tid == 0) {
                const unsigned a2 = __hip_atomic_fetch_add(bar + L2CNT(grp), 1u, __ATOMIC_RELAXED, __HIP_MEMORY_SCOPE_AGENT);
                if (a2 == (unsigned)t * gsz - 1u) astore32(bar + L2FLG + grp, (unsigned)t);
            }
            // (G) deferred out-store: HBM ack drains behind the next wait
            if (cc < OO) {
                const f32x4 q = {cn[0], cn[1], cn[2], cn[3]};
                __builtin_nontemporal_store(q, (f32x4*)(out + (size_t)b * (TT * OO) + (size_t)(t - 1) * OO + cc));
            }
        }
    }
}

extern "C" void kernel_launch(void* const* d_in, const int* in_sizes, int n_in,
                              void* d_out, int out_size, void* d_ws, size_t ws_size,
                              hipStream_t stream)
{
    const float* data = (const float*)d_in[0];
    const float* Wih1 = (const float*)d_in[1];
    const float* Whh1 = (const float*)d_in[2];
    const float* bih1 = (const float*)d_in[3];
    const float* bhh1 = (const float*)d_in[4];
    const float* Wih2 = (const float*)d_in[5];
    const float* Whh2 = (const float*)d_in[6];
    const float* bih2 = (const float*)d_in[7];
    const float* bhh2 = (const float*)d_in[8];
    float* out = (float*)d_out;
    char* wsb  = (char*)d_ws;

    hipFuncSetAttribute((const void*)rnn_mfma, hipFuncAttributeMaxDynamicSharedMemorySize, (int)LDS_BYTES);
    hipMemsetAsync(wsb, 0, MEMSET_BYTES, stream);   // slabs + counters: replay-safe
    rnn_mfma<<<NBLK, 256, LDS_BYTES, stream>>>(data,
                                               Wih1, Whh1, bih1, bhh1,
                                               Wih2, Whh2, bih2, bhh2,
                                               wsb, out);
}

// Round 16
// 4211.126 us; speedup vs baseline: 1.2766x; 1.0568x over previous
//
#include <hip/hip_runtime.h>
#include <math.h>

#define BB 64
#define TT 512
#define FF 32
#define HH 512
#define OO 680

typedef _Float16 half8 __attribute__((ext_vector_type(8)));
typedef float f32x4 __attribute__((ext_vector_type(4)));

// ---- ws layout: act slabs in MFMA-B-fragment tile order, ping-pong by epoch parity ----
// tile(ks,bfrag) = 1KB; lane l owns 16B at l*16: k = ks*32+(l>>4)*8+j, batch = bfrag*16+(l&15).
#define H1S_OFF 0u          // 2 x 65536  (h1, 512 cols)
#define C1S_OFF 131072u     // 2 x 65536  (c1, 512 cols)
#define H2S_OFF 262144u     // 2 x 90112  (h2, 704 padded cols)
#define BAR_OFF 442368u
#define MEMSET_BYTES 443648u

#define NBLK 64
#define LDS_BYTES 151552u   // L1 weights 34KB + L2 weights 114KB
#define L2W_OFF 34816u      // byte offset of L2 weight tiles in LDS

// bar dword offsets: 8 arrival counters (one 128B line each) + 8 packed flags (one line)
#define CNT(g) ((g)*32)
#define FLG    256

__device__ __forceinline__ float sigf(float x) { return 1.f / (1.f + expf(-x)); }

__device__ __forceinline__ unsigned long long aload8(const void* p) {
    return __hip_atomic_load((const unsigned long long*)p, __ATOMIC_RELAXED, __HIP_MEMORY_SCOPE_AGENT);
}
__device__ __forceinline__ void astore8(void* p, unsigned long long v) {
    __hip_atomic_store((unsigned long long*)p, v, __ATOMIC_RELAXED, __HIP_MEMORY_SCOPE_AGENT);
}
__device__ __forceinline__ void astore32(unsigned* p, unsigned v) {
    __hip_atomic_store(p, v, __ATOMIC_RELAXED, __HIP_MEMORY_SCOPE_AGENT);
}
__device__ __forceinline__ half8 ld_act(const char* p) {
    union { unsigned long long u[2]; half8 h; } t;
    t.u[0] = aload8(p); t.u[1] = aload8(p + 8);
    return t.h;
}
__device__ __forceinline__ unsigned pack2h(float a, float b) {
    union { _Float16 h[2]; unsigned u; } t;
    t.h[0] = (_Float16)a; t.h[1] = (_Float16)b; return t.u;
}
__device__ __forceinline__ unsigned long long pack4h(float a, float b, float c, float d) {
    union { _Float16 h[4]; unsigned long long u; } t;
    t.h[0] = (_Float16)a; t.h[1] = (_Float16)b; t.h[2] = (_Float16)c; t.h[3] = (_Float16)d;
    return t.u;
}
// min over the 8 packed epoch flags (read-mostly line; one wave-uniform read)
__device__ __forceinline__ unsigned minFlag(const unsigned* bar) {
    const unsigned long long v0 = aload8(bar + FLG);
    const unsigned long long v1 = aload8(bar + FLG + 2);
    const unsigned long long v2 = aload8(bar + FLG + 4);
    const unsigned long long v3 = aload8(bar + FLG + 6);
    unsigned m = (unsigned)v0, x;
    x = (unsigned)(v0 >> 32); m = x < m ? x : m;
    x = (unsigned)v1;         m = x < m ? x : m;
    x = (unsigned)(v1 >> 32); m = x < m ? x : m;
    x = (unsigned)v2;         m = x < m ? x : m;
    x = (unsigned)(v2 >> 32); m = x < m ? x : m;
    x = (unsigned)v3;         m = x < m ? x : m;
    x = (unsigned)(v3 >> 32); m = x < m ? x : m;
    return m;
}
// slab write address for 4-col-aligned group cc, batch b
__device__ __forceinline__ size_t slab_waddr(int cc, int b) {
    return (size_t)((cc >> 5) * 4 + (b >> 4)) * 1024
         + (size_t)((((cc >> 3) & 3) * 16 + (b & 15))) * 16
         + (size_t)(cc & 7) * 2;
}

// Merged persistent MFMA kernel: 64 blocks x 256 threads, ONE sync domain.
// Block bk owns L1 cols [bk*8, bk*8+8) and L2 cols [bk*12, bk*12+12) (real < 680).
// Epoch s: L1 step s (s<TT) and L2 step s-1 (s>=1). One wait + one arrival per epoch.
// A-tile rows packed fq = col*4 + gate -> all-4-gates lane-local epilogue (no exchange).
__global__ __launch_bounds__(256, 1)
void rnn_merged(const float* __restrict__ data,
    const float* __restrict__ Wih1, const float* __restrict__ Whh1,
    const float* __restrict__ bih1, const float* __restrict__ bhh1,
    const float* __restrict__ Wih2, const float* __restrict__ Whh2,
    const float* __restrict__ bih2, const float* __restrict__ bhh2,
    char* __restrict__ wsb, float* __restrict__ out)
{
    extern __shared__ char lds[];
    const int tid = threadIdx.x, wv = tid >> 6, l = tid & 63;
    const int hi = l >> 4, lo = l & 15;
    const int bk = blockIdx.x;
    unsigned* bar = (unsigned*)(wsb + BAR_OFF);
    const int b = wv * 16 + lo;                 // this lane's batch

    // ---- one-time: convert weights fp32 -> fp16 into LDS (A-fragment tiles) ----
    // L1: 34 tiles (ks 0..16, q 0..1); row fq = q*16 + i; col = bk*8 + fq>>2; gate = fq&3.
    for (int u = tid; u < 34 * 256; u += 256) {
        const int tt = u >> 8, w = u & 255;
        const int ks = tt >> 1, q = tt & 1;
        const int ll = w >> 2, jj = w & 3;
        const int fq = q * 16 + (ll & 15);
        const int col = bk * 8 + (fq >> 2);
        const int gate = fq & 3;
        const int grow = gate * HH + col;
        const int k = ks * 32 + (ll >> 4) * 8 + jj * 2;
        const float v0 = (k < FF)     ? Wih1[(size_t)grow * FF + k]     : Whh1[(size_t)grow * HH + k - FF];
        const float v1 = (k + 1 < FF) ? Wih1[(size_t)grow * FF + k + 1] : Whh1[(size_t)grow * HH + k + 1 - FF];
        ((unsigned*)lds)[tt * 256 + w] = pack2h(v0, v1);
    }
    // L2: 114 tiles (ks 0..37, q 0..2); fq = q*16 + i; col = bk*12 + fq>>2; gate = fq&3.
    for (int u = tid; u < 114 * 256; u += 256) {
        const int tt = u >> 8, w = u & 255;
        const int ks = tt / 3, q = tt - ks * 3;
        const int ll = w >> 2, jj = w & 3;
        const int fq = q * 16 + (ll & 15);
        const int col = bk * 12 + (fq >> 2);
        const int gate = fq & 3;
        const int k = ks * 32 + (ll >> 4) * 8 + jj * 2;
        float v0 = 0.f, v1 = 0.f;
        if (col < OO) {
            if (k < HH) v0 = Wih2[((size_t)gate * OO + col) * HH + k];
            else if (k < 1192) v0 = Whh2[((size_t)gate * OO + col) * OO + k - HH];
            if (k + 1 < HH) v1 = Wih2[((size_t)gate * OO + col) * HH + k + 1];
            else if (k + 1 < 1192) v1 = Whh2[((size_t)gate * OO + col) * OO + k + 1 - HH];
        }
        ((unsigned*)(lds + L2W_OFF))[tt * 256 + w] = pack2h(v0, v1);
    }
    __syncthreads();

    // ---- bias hoist: lane-local (col = base + q*4 + hi, gate = r) ----
    float bs1[2][4], bs2[3][4];
    #pragma unroll
    for (int q = 0; q < 2; ++q) {
        const int col = bk * 8 + q * 4 + hi;
        #pragma unroll
        for (int g = 0; g < 4; ++g) bs1[q][g] = bih1[g * HH + col] + bhh1[g * HH + col];
    }
    #pragma unroll
    for (int q = 0; q < 3; ++q) {
        const int col = bk * 12 + q * 4 + hi;
        const bool ok = col < OO;
        #pragma unroll
        for (int g = 0; g < 4; ++g) bs2[q][g] = ok ? (bih2[g * OO + col] + bhh2[g * OO + col]) : 0.f;
    }
    float cr1[2] = {0.f, 0.f};
    float cr2[3] = {0.f, 0.f, 0.f};

    for (int s = 0; s <= TT; ++s) {
        const int wr = s & 1, rd = wr ^ 1;      // slab slot parity: write s&1, read (s-1)&1
        // ---- L1 x-part: loads + 2 MFMAs BEFORE the wait ----
        f32x4 a10 = {0,0,0,0}, a11 = {0,0,0,0};
        if (s < TT) {
            const float* xp = data + (size_t)b * (TT * FF) + (size_t)s * FF + hi * 8;
            const float4 xa = *(const float4*)xp;
            const float4 xb4 = *(const float4*)(xp + 4);
            half8 bx;
            bx[0] = (_Float16)xa.x; bx[1] = (_Float16)xa.y; bx[2] = (_Float16)xa.z; bx[3] = (_Float16)xa.w;
            bx[4] = (_Float16)xb4.x; bx[5] = (_Float16)xb4.y; bx[6] = (_Float16)xb4.z; bx[7] = (_Float16)xb4.w;
            a10 = __builtin_amdgcn_mfma_f32_16x16x32_f16(*(const half8*)(lds + (size_t)l * 16), bx, a10, 0, 0, 0);
            a11 = __builtin_amdgcn_mfma_f32_16x16x32_f16(*(const half8*)(lds + 1024 + (size_t)l * 16), bx, a11, 0, 0, 0);
        }
        // ---- THE single wait: epoch s-1 complete across all 64 blocks ----
        if (s > 0) {
            if (tid == 0) { while (minFlag(bar) < (unsigned)s) {} }
            __syncthreads();
        }
        float pend[4]; float* pendP = nullptr;   // deferred out store

        // ================= L1 part: step s =================
        if (s < TT) {
            const char* h1p = wsb + H1S_OFF + (size_t)rd * 65536u + (size_t)l * 16;
            half8 bh[16];
            #pragma unroll
            for (int ks = 0; ks < 16; ++ks) bh[ks] = ld_act(h1p + (size_t)(ks * 4 + wv) * 1024);
            #pragma unroll
            for (int ks = 1; ks <= 16; ++ks) {
                a10 = __builtin_amdgcn_mfma_f32_16x16x32_f16(*(const half8*)(lds + (size_t)(ks * 2) * 1024 + (size_t)l * 16), bh[ks - 1], a10, 0, 0, 0);
                a11 = __builtin_amdgcn_mfma_f32_16x16x32_f16(*(const half8*)(lds + (size_t)(ks * 2 + 1) * 1024 + (size_t)l * 16), bh[ks - 1], a11, 0, 0, 0);
            }
            // lane-local epilogue (gate = reg index r)
            float cn1[2], hn1[2];
            #pragma unroll
            for (int q = 0; q < 2; ++q) {
                const f32x4 a = (q == 0) ? a10 : a11;
                const float ig = sigf(a[0] + bs1[q][0]);
                const float fg = sigf(a[1] + bs1[q][1]);
                const float gg = tanhf(a[2] + bs1[q][2]);
                const float og = sigf(a[3] + bs1[q][3]);
                const float c = fg * cr1[q] + ig * gg;
                cr1[q] = c;
                cn1[q] = c; hn1[q] = og * tanhf(c);
            }
            // gather 4 adjacent cols (lanes hi=0..3, same lo) -> writer hi==q
            char* h1w = wsb + H1S_OFF + (size_t)wr * 65536u;
            char* c1w = wsb + C1S_OFF + (size_t)wr * 65536u;
            #pragma unroll
            for (int q = 0; q < 2; ++q) {
                const float h0 = __shfl(hn1[q], lo), h1v = __shfl(hn1[q], 16 + lo);
                const float h2v = __shfl(hn1[q], 32 + lo), h3 = __shfl(hn1[q], 48 + lo);
                const float c0 = __shfl(cn1[q], lo), c1v = __shfl(cn1[q], 16 + lo);
                const float c2v = __shfl(cn1[q], 32 + lo), c3 = __shfl(cn1[q], 48 + lo);
                if (hi == q) {
                    const int cc = bk * 8 + q * 4;
                    const size_t ad = slab_waddr(cc, b);
                    astore8(h1w + ad, pack4h(h0, h1v, h2v, h3));
                    astore8(c1w + ad, pack4h(c0, c1v, c2v, c3));
                }
            }
        }
        // ================= L2 part: step s-1 =================
        if (s >= 1) {
            f32x4 a20 = {0,0,0,0}, a21 = {0,0,0,0}, a22 = {0,0,0,0};
            const char* c1p = wsb + C1S_OFF + (size_t)rd * 65536u + (size_t)l * 16;
            half8 bc[16];
            #pragma unroll
            for (int ks = 0; ks < 16; ++ks) bc[ks] = ld_act(c1p + (size_t)(ks * 4 + wv) * 1024);
            #pragma unroll
            for (int ks = 0; ks < 16; ++ks) {
                const char* at = lds + L2W_OFF + (size_t)(ks * 3) * 1024 + (size_t)l * 16;
                a20 = __builtin_amdgcn_mfma_f32_16x16x32_f16(*(const half8*)(at       ), bc[ks], a20, 0, 0, 0);
                a21 = __builtin_amdgcn_mfma_f32_16x16x32_f16(*(const half8*)(at + 1024), bc[ks], a21, 0, 0, 0);
                a22 = __builtin_amdgcn_mfma_f32_16x16x32_f16(*(const half8*)(at + 2048), bc[ks], a22, 0, 0, 0);
            }
            const char* h2p = wsb + H2S_OFF + (size_t)rd * 90112u + (size_t)l * 16;
            half8 bh2[22];
            #pragma unroll
            for (int kk = 0; kk < 22; ++kk) bh2[kk] = ld_act(h2p + (size_t)(kk * 4 + wv) * 1024);
            #pragma unroll
            for (int kk = 0; kk < 22; ++kk) {
                const char* at = lds + L2W_OFF + (size_t)((16 + kk) * 3) * 1024 + (size_t)l * 16;
                a20 = __builtin_amdgcn_mfma_f32_16x16x32_f16(*(const half8*)(at       ), bh2[kk], a20, 0, 0, 0);
                a21 = __builtin_amdgcn_mfma_f32_16x16x32_f16(*(const half8*)(at + 1024), bh2[kk], a21, 0, 0, 0);
                a22 = __builtin_amdgcn_mfma_f32_16x16x32_f16(*(const half8*)(at + 2048), bh2[kk], a22, 0, 0, 0);
            }
            // lane-local epilogue
            float cn2[3], hn2[3];
            #pragma unroll
            for (int q = 0; q < 3; ++q) {
                const f32x4 a = (q == 0) ? a20 : (q == 1) ? a21 : a22;
                const float ig = sigf(a[0] + bs2[q][0]);
                const float fg = sigf(a[1] + bs2[q][1]);
                const float gg = tanhf(a[2] + bs2[q][2]);
                const float og = sigf(a[3] + bs2[q][3]);
                const float c = fg * cr2[q] + ig * gg;
                cr2[q] = c;
                cn2[q] = c; hn2[q] = og * tanhf(c);
            }
            char* h2w = wsb + H2S_OFF + (size_t)wr * 90112u;
            #pragma unroll
            for (int q = 0; q < 3; ++q) {
                const float h0 = __shfl(hn2[q], lo), h1v = __shfl(hn2[q], 16 + lo);
                const float h2v = __shfl(hn2[q], 32 + lo), h3 = __shfl(hn2[q], 48 + lo);
                const float c0 = __shfl(cn2[q], lo), c1v = __shfl(cn2[q], 16 + lo);
                const float c2v = __shfl(cn2[q], 32 + lo), c3 = __shfl(cn2[q], 48 + lo);
                if (hi == q) {
                    const int cc = bk * 12 + q * 4;
                    if (cc + 4 <= OO) {            // 680 % 4 == 0: groups all-real or all-pad
                        astore8(h2w + slab_waddr(cc, b), pack4h(h0, h1v, h2v, h3));
                        pend[0] = c0; pend[1] = c1v; pend[2] = c2v; pend[3] = c3;
                        pendP = out + (size_t)b * (TT * OO) + (size_t)(s - 1) * OO + cc;
                    }
                }
            }
        }
        // ---- single arrival (skip final epoch; nobody waits on it) ----
        __syncthreads();
        if (s < TT && tid == 0) {
            const int g = bk & 7;
            const unsigned e = (unsigned)(s + 1);
            const unsigned a = __hip_atomic_fetch_add(bar + CNT(g), 1u, __ATOMIC_RELAXED, __HIP_MEMORY_SCOPE_AGENT);
            if (a == e * 8u - 1u) astore32(bar + FLG + g, e);
        }
        // ---- deferred out store: HBM ack drains behind the next wait ----
        if (pendP) {
            const f32x4 q4 = {pend[0], pend[1], pend[2], pend[3]};
            __builtin_nontemporal_store(q4, (f32x4*)pendP);
        }
    }
}

extern "C" void kernel_launch(void* const* d_in, const int* in_sizes, int n_in,
                              void* d_out, int out_size, void* d_ws, size_t ws_size,
                              hipStream_t stream)
{
    const float* data = (const float*)d_in[0];
    const float* Wih1 = (const float*)d_in[1];
    const float* Whh1 = (const float*)d_in[2];
    const float* bih1 = (const float*)d_in[3];
    const float* bhh1 = (const float*)d_in[4];
    const float* Wih2 = (const float*)d_in[5];
    const float* Whh2 = (const float*)d_in[6];
    const float* bih2 = (const float*)d_in[7];
    const float* bhh2 = (const float*)d_in[8];
    float* out = (float*)d_out;
    char* wsb  = (char*)d_ws;

    hipFuncSetAttribute((const void*)rnn_merged, hipFuncAttributeMaxDynamicSharedMemorySize, (int)LDS_BYTES);
    hipMemsetAsync(wsb, 0, MEMSET_BYTES, stream);   // slabs + counters/flags: replay-safe
    rnn_merged<<<NBLK, 256, LDS_BYTES, stream>>>(data,
                                                 Wih1, Whh1, bih1, bhh1,
                                                 Wih2, Whh2, bih2, bhh2,
                                                 wsb, out);
}